// Round 4
// baseline (232.678 us; speedup 1.0000x reference)
//
#include <hip/hip_runtime.h>
#include <hip/hip_bf16.h>

typedef __attribute__((ext_vector_type(8))) short short8;
typedef __attribute__((ext_vector_type(4))) float f32x4;
typedef __attribute__((ext_vector_type(4))) unsigned int u32x4;

#define WT_PITCH 264                    // 256 + 8 bf16 pad -> 528B rows, 16B aligned
#define LDS_A (256 * WT_PITCH * 2)      // 135168 B dynamic LDS for node_proj

static __device__ __forceinline__ short bf16s(float f) {
    __hip_bfloat16 h = __float2bfloat16(f);
    return __builtin_bit_cast(short, h);
}
static __device__ __forceinline__ float uplo(unsigned int u) {
    unsigned int b = u << 16;
    return __builtin_bit_cast(float, b);
}
static __device__ __forceinline__ float uphi(unsigned int u) {
    unsigned int b = u & 0xffff0000u;
    return __builtin_bit_cast(float, b);
}

// ---------------------------------------------------------------------------
// Kernel 0: detect whether edge_index is int64 or int32.
// int64 data: every u64 word is a valid index < 50000 < 2^32 -> high half 0.
// int32 data: words pack two random indices -> some high half nonzero a.s.
__global__ void idx_detect_kernel(const unsigned long long* __restrict__ ei,
                                  int nwords, int* __restrict__ flag) {
    __shared__ int ok;
    if (threadIdx.x == 0) ok = 1;
    __syncthreads();
    bool good = true;
    for (int i = threadIdx.x; i < nwords; i += blockDim.x)
        if (ei[i] >> 32) good = false;
    if (!good) ok = 0;   // racy benign write
    __syncthreads();
    if (threadIdx.x == 0) *flag = ok;   // 1 -> int64, 0 -> int32
}

// ---------------------------------------------------------------------------
// Kernel 1: UV[n][cc] = sum_k emb[n][k] * Wbig[k][cc]  (bf16 out, f32 acc)
// Wbig[k][cc] = cc<128 ? W1[k][cc] : W1[256+k][cc-128]
// MFMA 16x16x32 bf16. Wave tile = 16 nodes x 256 cols. B staged transposed
// in LDS: WT[cc][k], pitch 264. A-frags loaded directly from global.
__global__ __launch_bounds__(256) void node_proj_kernel(
    const float* __restrict__ emb, const float* __restrict__ W1,
    __hip_bfloat16* __restrict__ UV, int N) {
    extern __shared__ short WT[];
    const int tid = threadIdx.x;
    // stage Wbig^T as bf16 (f32x4 coalesced global reads; one-time LDS scatter)
    for (int i = tid; i < 64 * 256; i += 256) {
        int cc = (i & 63) * 4, k = i >> 6;
        f32x4 v = (cc < 128) ? *(const f32x4*)(W1 + k * 128 + cc)
                             : *(const f32x4*)(W1 + (256 + k) * 128 + (cc - 128));
#pragma unroll
        for (int j = 0; j < 4; ++j) WT[(cc + j) * WT_PITCH + k] = bf16s(v[j]);
    }
    __syncthreads();
    const int lane = tid & 63;
    const int c = lane & 15, g = lane >> 4;
    const int wglob = blockIdx.x * 4 + (tid >> 6);
    const int nTiles = N >> 4;          // 16 | N (50000/16 = 3125)
    for (int t = wglob; t < nTiles; t += gridDim.x * 4) {
        // lane reads row (t*16+c), k-slices kk*32 + 8g .. +8 (each row once/wave)
        const float* arow = emb + (size_t)(t * 16 + c) * 256 + 8 * g;
        f32x4 a0[8], a1[8];
#pragma unroll
        for (int kk = 0; kk < 8; ++kk) {
            a0[kk] = *(const f32x4*)(arow + kk * 32);
            a1[kk] = *(const f32x4*)(arow + kk * 32 + 4);
        }
        f32x4 acc[16];
#pragma unroll
        for (int ct = 0; ct < 16; ++ct) acc[ct] = f32x4{0.f, 0.f, 0.f, 0.f};
#pragma unroll
        for (int kk = 0; kk < 8; ++kk) {
            short8 af;
#pragma unroll
            for (int j = 0; j < 4; ++j) {
                af[j] = bf16s(a0[kk][j]);
                af[4 + j] = bf16s(a1[kk][j]);
            }
            const int kb = kk * 32 + 8 * g;
#pragma unroll
            for (int ct = 0; ct < 16; ++ct) {
                short8 bf = *(const short8*)(WT + (ct * 16 + c) * WT_PITCH + kb);
                acc[ct] = __builtin_amdgcn_mfma_f32_16x16x32_bf16(af, bf, acc[ct], 0, 0, 0);
            }
        }
        // D layout: col = lane&15, row = (lane>>4)*4 + r   [m89]
        __hip_bfloat16* orow = UV + (size_t)(t * 16 + g * 4) * 256 + c;
#pragma unroll
        for (int ct = 0; ct < 16; ++ct)
#pragma unroll
            for (int r = 0; r < 4; ++r)
                orow[(size_t)r * 256 + ct * 16] = __float2bfloat16(acc[ct][r]);
    }
}

// ---------------------------------------------------------------------------
// Kernel 2: fused edge MLP. One wave <-> groups of 16 edges, grid-stride.
// h1 = relu(U[src] + V[dst] + b1) built directly in A-frag layout;
// layer2 via MFMA with register-hoisted W2 frags; layer3 via shfl reduce.
__global__ __launch_bounds__(256, 3) void edge_mlp_kernel(
    const __hip_bfloat16* __restrict__ UV, const void* __restrict__ eidx,
    const int* __restrict__ flag, const float* __restrict__ b1,
    const float* __restrict__ W2, const float* __restrict__ b2,
    const float* __restrict__ W3, const float* __restrict__ b3,
    float* __restrict__ out, int E) {
    __shared__ short W2T[64][136];      // W2 transposed, bf16, padded pitch
    __shared__ float b1s[128];
    const int tid = threadIdx.x;
    for (int i = tid; i < 128 * 64; i += 256) {
        int cc = i & 63, k = i >> 6;
        W2T[cc][k] = bf16s(W2[k * 64 + cc]);
    }
    if (tid < 128) b1s[tid] = b1[tid];
    __syncthreads();
    const int lane = tid & 63;
    const int c = lane & 15, g = lane >> 4;
    // hoist W2 B-frags into registers (constant across all edges)
    short8 wf[4][4];
#pragma unroll
    for (int ct = 0; ct < 4; ++ct)
#pragma unroll
        for (int kk = 0; kk < 4; ++kk)
            wf[ct][kk] = *(const short8*)(&W2T[ct * 16 + c][kk * 32 + 8 * g]);
    float w3f[4], b2f[4];
#pragma unroll
    for (int ct = 0; ct < 4; ++ct) {
        w3f[ct] = W3[ct * 16 + c];
        b2f[ct] = b2[ct * 16 + c];
    }
    const float b3v = b3[0];
    const bool is64 = (*flag != 0);
    const int* ei32 = (const int*)eidx;
    const long long* ei64 = (const long long*)eidx;
    const int wglob = blockIdx.x * 4 + (tid >> 6);
    const int nG = E >> 4;              // 16 | E
    for (int grp = wglob; grp < nG; grp += gridDim.x * 4) {
        const int e = grp * 16 + c;     // A-frag row c <-> edge e
        int src, dst;
        if (is64) { src = (int)ei64[e]; dst = (int)ei64[E + e]; }
        else      { src = ei32[e];      dst = ei32[E + e]; }
        // gather u/v slices: 16B each, already in A-frag (row c, k = kk*32+8g+j)
        // order; the 4 g-lanes of an edge cover one 64B line per kk.
        const u32x4* up = (const u32x4*)(UV + (size_t)src * 256) + g;
        const u32x4* vp = (const u32x4*)(UV + (size_t)dst * 256 + 128) + g;
        u32x4 ur[4], vr[4];
#pragma unroll
        for (int kk = 0; kk < 4; ++kk) { ur[kk] = up[kk * 4]; vr[kk] = vp[kk * 4]; }
        f32x4 acc[4];
#pragma unroll
        for (int ct = 0; ct < 4; ++ct) acc[ct] = f32x4{0.f, 0.f, 0.f, 0.f};
#pragma unroll
        for (int kk = 0; kk < 4; ++kk) {
            const float* bp = b1s + kk * 32 + 8 * g;
            short8 af;
#pragma unroll
            for (int j = 0; j < 4; ++j) {
                float h0 = fmaxf(uplo(ur[kk][j]) + uplo(vr[kk][j]) + bp[2 * j], 0.f);
                float h1 = fmaxf(uphi(ur[kk][j]) + uphi(vr[kk][j]) + bp[2 * j + 1], 0.f);
                af[2 * j] = bf16s(h0);
                af[2 * j + 1] = bf16s(h1);
            }
#pragma unroll
            for (int ct = 0; ct < 4; ++ct)
                acc[ct] = __builtin_amdgcn_mfma_f32_16x16x32_bf16(af, wf[ct][kk], acc[ct], 0, 0, 0);
        }
        // layer 3: h2 = relu(acc + b2); logit = h2 . W3 summed over 64 channels
        float p0 = 0.f, p1 = 0.f, p2 = 0.f, p3 = 0.f;
#pragma unroll
        for (int ct = 0; ct < 4; ++ct) {
            p0 = fmaf(fmaxf(acc[ct][0] + b2f[ct], 0.f), w3f[ct], p0);
            p1 = fmaf(fmaxf(acc[ct][1] + b2f[ct], 0.f), w3f[ct], p1);
            p2 = fmaf(fmaxf(acc[ct][2] + b2f[ct], 0.f), w3f[ct], p2);
            p3 = fmaf(fmaxf(acc[ct][3] + b2f[ct], 0.f), w3f[ct], p3);
        }
#pragma unroll
        for (int off = 8; off >= 1; off >>= 1) {
            p0 += __shfl_xor(p0, off);
            p1 += __shfl_xor(p1, off);
            p2 += __shfl_xor(p2, off);
            p3 += __shfl_xor(p3, off);
        }
        if (c < 4) {
            float pc = (c == 0) ? p0 : (c == 1) ? p1 : (c == 2) ? p2 : p3;
            out[grp * 16 + g * 4 + c] = 1.f / (1.f + __expf(-(pc + b3v)));
        }
    }
}

// ---------------------------------------------------------------------------
extern "C" void kernel_launch(void* const* d_in, const int* in_sizes, int n_in,
                              void* d_out, int out_size, void* d_ws, size_t ws_size,
                              hipStream_t stream) {
    const float* emb = (const float*)d_in[0];
    const void* eidx = d_in[1];
    const float* W1 = (const float*)d_in[2];
    const float* b1 = (const float*)d_in[3];
    const float* W2 = (const float*)d_in[4];
    const float* b2 = (const float*)d_in[5];
    const float* W3 = (const float*)d_in[6];
    const float* b3 = (const float*)d_in[7];
    float* out = (float*)d_out;

    const int N = in_sizes[0] / 256;    // 50000 nodes
    const int E = in_sizes[1] / 2;      // 800000 edges (elements/2 either dtype)

    int* flag = (int*)d_ws;
    __hip_bfloat16* UV = (__hip_bfloat16*)((char*)d_ws + 256);  // N x 256 bf16

    idx_detect_kernel<<<1, 256, 0, stream>>>(
        (const unsigned long long*)eidx, 4096, flag);

    hipFuncSetAttribute((const void*)node_proj_kernel,
                        hipFuncAttributeMaxDynamicSharedMemorySize, LDS_A);
    node_proj_kernel<<<256, 256, LDS_A, stream>>>(emb, W1, UV, N);

    edge_mlp_kernel<<<768, 256, 0, stream>>>(UV, eidx, flag, b1, W2, b2, W3, b3,
                                             out, E);
}

// Round 8
// 171.514 us; speedup vs baseline: 1.3566x; 1.3566x over previous
//
#include <hip/hip_runtime.h>
#include <hip/hip_bf16.h>

typedef __attribute__((ext_vector_type(8))) short short8;
typedef __attribute__((ext_vector_type(4))) float f32x4;
typedef __attribute__((ext_vector_type(4))) unsigned int u32x4;

#define WT_PITCH 264                    // 256 + 8 bf16 pad -> 528B rows, 16B aligned
#define WT_BYTES (256 * WT_PITCH * 2)   // 135168 B (LDS + global staging copy)

static __device__ __forceinline__ short bf16s(float f) {
    __hip_bfloat16 h = __float2bfloat16(f);
    return __builtin_bit_cast(short, h);
}
static __device__ __forceinline__ float uplo(unsigned int u) {
    unsigned int b = u << 16;
    return __builtin_bit_cast(float, b);
}
static __device__ __forceinline__ float uphi(unsigned int u) {
    unsigned int b = u & 0xffff0000u;
    return __builtin_bit_cast(float, b);
}

// ---------------------------------------------------------------------------
// Kernel 0 "prep": (a) block 0 detects int64-vs-int32 edge_index;
// (b) all blocks transpose W1 -> Wbig^T bf16 (padded pitch 264) into global ws.
// Wbig[k][cc] = cc<128 ? W1[k][cc] : W1[256+k][cc-128];  wtg[cc][k] layout.
__global__ __launch_bounds__(1024) void prep_kernel(
    const float* __restrict__ W1, const unsigned long long* __restrict__ ei,
    short* __restrict__ wtg, int* __restrict__ flag) {
    const int tid = threadIdx.x;
    if (blockIdx.x == 0) {
        __shared__ int ok;
        if (tid == 0) ok = 1;
        __syncthreads();
        bool good = true;
        for (int i = tid; i < 4096; i += 1024)
            if (ei[i] >> 32) good = false;
        if (!good) ok = 0;   // racy benign write
        __syncthreads();
        if (tid == 0) *flag = ok;   // 1 -> int64, 0 -> int32
    }
#pragma unroll
    for (int j = 0; j < 8; ++j) {
        int i = blockIdx.x * 8192 + j * 1024 + tid;   // 8 blocks x 8192 = 65536
        int cc = i & 255, k = i >> 8;
        float v = (cc < 128) ? W1[k * 128 + cc] : W1[(256 + k) * 128 + (cc - 128)];
        wtg[cc * WT_PITCH + k] = bf16s(v);
    }
}

// ---------------------------------------------------------------------------
// Kernel 1: UV[n][cc] = sum_k emb[n][k] * Wbig[k][cc]  (bf16 out, f32 acc)
// 1024-thread blocks (16 waves/CU = 4/SIMD), VGPR capped at 128.
// W^T staged LINEARLY from global wtg (coalesced short8 -> ds_write_b128,
// bank-even) -> no transpose-scatter conflicts. One 16-node tile per wave.
__global__ __launch_bounds__(1024, 4) void node_proj_kernel(
    const float* __restrict__ emb, const short* __restrict__ wtg,
    __hip_bfloat16* __restrict__ UV, int N) {
    extern __shared__ short WT[];
    const int tid = threadIdx.x;
    const int wid = tid >> 6, lane = tid & 63;
    // stage 135168 B = 132 chunks of 1024 B, linear (identity layout copy)
    for (int it = wid; it < 132; it += 16) {
        const short8 v = *(const short8*)((const char*)wtg + it * 1024 + lane * 16);
        *(short8*)((char*)WT + it * 1024 + lane * 16) = v;
    }
    __syncthreads();
    const int c = lane & 15, g = lane >> 4;
    const int t = wid * 256 + blockIdx.x;     // balanced wave->tile map, <=1 tile
    if (t < (N >> 4)) {
        const float* arow = emb + (size_t)(t * 16 + c) * 256 + 8 * g;
        f32x4 acc[16];
#pragma unroll
        for (int ct = 0; ct < 16; ++ct) acc[ct] = f32x4{0.f, 0.f, 0.f, 0.f};
#pragma unroll
        for (int kk = 0; kk < 8; ++kk) {
            f32x4 p = *(const f32x4*)(arow + kk * 32);
            f32x4 q = *(const f32x4*)(arow + kk * 32 + 4);
            short8 af;
#pragma unroll
            for (int j = 0; j < 4; ++j) {
                af[j] = bf16s(p[j]);
                af[4 + j] = bf16s(q[j]);
            }
            const short* wrow = WT + kk * 32 + 8 * g;
#pragma unroll
            for (int ct = 0; ct < 16; ++ct) {
                short8 bf = *(const short8*)(wrow + (ct * 16 + c) * WT_PITCH);
                acc[ct] = __builtin_amdgcn_mfma_f32_16x16x32_bf16(af, bf, acc[ct], 0, 0, 0);
            }
        }
        // D layout: col = lane&15, row = (lane>>4)*4 + r   [m89]
        // r-outer / ct-inner: adjacent 32B segments -> L2 write-combine
#pragma unroll
        for (int r = 0; r < 4; ++r) {
            __hip_bfloat16* orow = UV + (size_t)(t * 16 + g * 4 + r) * 256 + c;
#pragma unroll
            for (int ct = 0; ct < 16; ++ct)
                orow[ct * 16] = __float2bfloat16(acc[ct][r]);
        }
    }
}

// ---------------------------------------------------------------------------
// Kernel 2: fused edge MLP. One wave <-> groups of 16 edges, grid-stride.
// h1 = relu(U[src] + V[dst] + b1) built directly in A-frag layout;
// layer2 via MFMA with register-hoisted W2 frags; layer3 via shfl reduce.
__global__ __launch_bounds__(256, 3) void edge_mlp_kernel(
    const __hip_bfloat16* __restrict__ UV, const void* __restrict__ eidx,
    const int* __restrict__ flag, const float* __restrict__ b1,
    const float* __restrict__ W2, const float* __restrict__ b2,
    const float* __restrict__ W3, const float* __restrict__ b3,
    float* __restrict__ out, int E) {
    __shared__ short W2T[64][136];      // W2 transposed, bf16, padded pitch
    __shared__ float b1s[128];
    const int tid = threadIdx.x;
    for (int i = tid; i < 128 * 64; i += 256) {
        int cc = i & 63, k = i >> 6;
        W2T[cc][k] = bf16s(W2[k * 64 + cc]);
    }
    if (tid < 128) b1s[tid] = b1[tid];
    __syncthreads();
    const int lane = tid & 63;
    const int c = lane & 15, g = lane >> 4;
    // hoist W2 B-frags into registers (constant across all edges)
    short8 wf[4][4];
#pragma unroll
    for (int ct = 0; ct < 4; ++ct)
#pragma unroll
        for (int kk = 0; kk < 4; ++kk)
            wf[ct][kk] = *(const short8*)(&W2T[ct * 16 + c][kk * 32 + 8 * g]);
    float w3f[4], b2f[4];
#pragma unroll
    for (int ct = 0; ct < 4; ++ct) {
        w3f[ct] = W3[ct * 16 + c];
        b2f[ct] = b2[ct * 16 + c];
    }
    const float b3v = b3[0];
    const bool is64 = (*flag != 0);
    const int* ei32 = (const int*)eidx;
    const long long* ei64 = (const long long*)eidx;
    const int wglob = blockIdx.x * 4 + (tid >> 6);
    const int nG = E >> 4;              // 16 | E
    for (int grp = wglob; grp < nG; grp += gridDim.x * 4) {
        const int e = grp * 16 + c;     // A-frag row c <-> edge e
        int src, dst;
        if (is64) { src = (int)ei64[e]; dst = (int)ei64[E + e]; }
        else      { src = ei32[e];      dst = ei32[E + e]; }
        // gather u/v slices: 16B each, already in A-frag (row c, k = kk*32+8g+j)
        // order; the 4 g-lanes of an edge cover one 64B line per kk.
        const u32x4* up = (const u32x4*)(UV + (size_t)src * 256) + g;
        const u32x4* vp = (const u32x4*)(UV + (size_t)dst * 256 + 128) + g;
        u32x4 ur[4], vr[4];
#pragma unroll
        for (int kk = 0; kk < 4; ++kk) { ur[kk] = up[kk * 4]; vr[kk] = vp[kk * 4]; }
        f32x4 acc[4];
#pragma unroll
        for (int ct = 0; ct < 4; ++ct) acc[ct] = f32x4{0.f, 0.f, 0.f, 0.f};
#pragma unroll
        for (int kk = 0; kk < 4; ++kk) {
            const float* bp = b1s + kk * 32 + 8 * g;
            short8 af;
#pragma unroll
            for (int j = 0; j < 4; ++j) {
                float h0 = fmaxf(uplo(ur[kk][j]) + uplo(vr[kk][j]) + bp[2 * j], 0.f);
                float h1 = fmaxf(uphi(ur[kk][j]) + uphi(vr[kk][j]) + bp[2 * j + 1], 0.f);
                af[2 * j] = bf16s(h0);
                af[2 * j + 1] = bf16s(h1);
            }
#pragma unroll
            for (int ct = 0; ct < 4; ++ct)
                acc[ct] = __builtin_amdgcn_mfma_f32_16x16x32_bf16(af, wf[ct][kk], acc[ct], 0, 0, 0);
        }
        // layer 3: h2 = relu(acc + b2); logit = h2 . W3 summed over 64 channels
        float p0 = 0.f, p1 = 0.f, p2 = 0.f, p3 = 0.f;
#pragma unroll
        for (int ct = 0; ct < 4; ++ct) {
            p0 = fmaf(fmaxf(acc[ct][0] + b2f[ct], 0.f), w3f[ct], p0);
            p1 = fmaf(fmaxf(acc[ct][1] + b2f[ct], 0.f), w3f[ct], p1);
            p2 = fmaf(fmaxf(acc[ct][2] + b2f[ct], 0.f), w3f[ct], p2);
            p3 = fmaf(fmaxf(acc[ct][3] + b2f[ct], 0.f), w3f[ct], p3);
        }
#pragma unroll
        for (int off = 8; off >= 1; off >>= 1) {
            p0 += __shfl_xor(p0, off);
            p1 += __shfl_xor(p1, off);
            p2 += __shfl_xor(p2, off);
            p3 += __shfl_xor(p3, off);
        }
        if (c < 4) {
            float pc = (c == 0) ? p0 : (c == 1) ? p1 : (c == 2) ? p2 : p3;
            out[grp * 16 + g * 4 + c] = 1.f / (1.f + __expf(-(pc + b3v)));
        }
    }
}

// ---------------------------------------------------------------------------
extern "C" void kernel_launch(void* const* d_in, const int* in_sizes, int n_in,
                              void* d_out, int out_size, void* d_ws, size_t ws_size,
                              hipStream_t stream) {
    const float* emb = (const float*)d_in[0];
    const void* eidx = d_in[1];
    const float* W1 = (const float*)d_in[2];
    const float* b1 = (const float*)d_in[3];
    const float* W2 = (const float*)d_in[4];
    const float* b2 = (const float*)d_in[5];
    const float* W3 = (const float*)d_in[6];
    const float* b3 = (const float*)d_in[7];
    float* out = (float*)d_out;

    const int N = in_sizes[0] / 256;    // 50000 nodes
    const int E = in_sizes[1] / 2;      // 800000 edges (elements/2 either dtype)

    // ws layout: [0,256): flag | [256, 256+N*512): UV bf16 | then wtg (135 KB)
    int* flag = (int*)d_ws;
    __hip_bfloat16* UV = (__hip_bfloat16*)((char*)d_ws + 256);
    short* wtg = (short*)((char*)d_ws + 256 + (size_t)N * 512);

    prep_kernel<<<8, 1024, 0, stream>>>(W1, (const unsigned long long*)eidx,
                                        wtg, flag);

    hipFuncSetAttribute((const void*)node_proj_kernel,
                        hipFuncAttributeMaxDynamicSharedMemorySize, WT_BYTES);
    node_proj_kernel<<<256, 1024, WT_BYTES, stream>>>(emb, wtg, UV, N);

    edge_mlp_kernel<<<768, 256, 0, stream>>>(UV, eidx, flag, b1, W2, b2, W3, b3,
                                             out, E);
}